// Round 10
// baseline (31.956 us; speedup 1.0000x reference)
//
#include <hip/hip_runtime.h>
#include <hip/hip_bf16.h>

// ---------------------------------------------------------------------------
// VQC_Net: probs[b, c] = ( sum_j U[c][j] * amp[b][j] )^2,  c = 0..9
// Structure: T = U rows 0..9 precomputed to d_ws by build_T; main kernel
// reads T with wave-uniform indices (s_load, K$-hot), c-outer matvec,
// wave-private LDS staging (no barriers, R8), persistent tiles + x prefetch.
// R9/R10 delta: (1) TILES=2 -> 4096 blocks = 2 generations/CU so gen 2
// backfills gen 1's drain; (2) nontemporal loads/stores for the x/out
// streams (each touched exactly once — don't churn L2/L3). NT builtins need
// native vector types, not HIP_vector_type -> use ext_vector_type alias.
// Lessons kept: LDS transpose essential (R7: direct stride-40B stores = 10x
// line-request amplification -> 2.2 TB/s); no vmcnt-draining barriers (R6);
// LDS-read matvec = DS-pipe bottleneck (R4); s_load matvec (R1).
// amp build:
//   amp[0][k]  = prod_j ( (k>>j)&1 ? x0j : 1-x0j )                 (no sqrt)
//   amp[b][k]  = sqrt(hi)*sqrt(lo) factored, big-endian bits       (b >= 1)
// ---------------------------------------------------------------------------

typedef float f32x4 __attribute__((ext_vector_type(4)));

#if defined(__has_builtin)
#if __has_builtin(__builtin_amdgcn_sqrtf)
#define FSQRT(x) __builtin_amdgcn_sqrtf(x)
#endif
#endif
#ifndef FSQRT
#define FSQRT(x) sqrtf(x)
#endif

__device__ __forceinline__ float ry_el(float c, float s, int i, int j) {
    return (i == j) ? c : (i ? s : -s);  // ry = [[c,-s],[s,c]]
}

__global__ void build_T(const float* __restrict__ theta, float* __restrict__ T) {
    int t = threadIdx.x;
    if (t >= 160) return;
    int c = t >> 4;   // row of U (class)
    int j = t & 15;   // col of U (amp index)

    float co1[4], si1[4], co2[4], si2[4];
#pragma unroll
    for (int q = 0; q < 4; ++q) {
        float h1 = 0.5f * theta[q];
        float h2 = 0.5f * theta[4 + q];
        co1[q] = cosf(h1); si1[q] = sinf(h1);
        co2[q] = cosf(h2); si2[q] = sinf(h2);
    }
    float acc = 0.0f;
#pragma unroll
    for (int k = 0; k < 16; ++k) {
        int k0 = k & 1, k1 = (k >> 1) & 1, k2 = (k >> 2) & 1, k3 = (k >> 3) & 1;
        float r2 = ry_el(co2[0], si2[0], c & 1, k0)
                 * ry_el(co2[1], si2[1], (c >> 1) & 1, k1)
                 * ry_el(co2[2], si2[2], (c >> 2) & 1, k2)
                 * ry_el(co2[3], si2[3], (c >> 3) & 1, k3);
        float r1 = ry_el(co1[0], si1[0], k0, j & 1)
                 * ry_el(co1[1], si1[1], k1, (j >> 1) & 1)
                 * ry_el(co1[2], si1[2], k2, (j >> 2) & 1)
                 * ry_el(co1[3], si1[3], k3, (j >> 3) & 1);
        int sgn = (k0 & k1) ^ (k1 & k2) ^ (k2 & k3) ^ (k0 & k3);
        acc = fmaf(sgn ? -r2 : r2, r1, acc);
    }
    T[c * 16 + j] = acc;   // row-major, matches matvec read order
}

// amp for the generic (b>=1) path: big-endian bits, squared probs, sqrt
__device__ __forceinline__ void amp_resolve(f32x4 xv, float amp[16]) {
    float p0 = xv.x * xv.x, p1 = xv.y * xv.y;
    float p2 = xv.z * xv.z, p3 = xv.w * xv.w;
    float hi[4] = { (1.0f - p0) * (1.0f - p1), (1.0f - p0) * p1,
                    p0 * (1.0f - p1),          p0 * p1 };
    float lo[4] = { (1.0f - p2) * (1.0f - p3), (1.0f - p2) * p3,
                    p2 * (1.0f - p3),          p2 * p3 };
    float sh[4], sl[4];
#pragma unroll
    for (int i = 0; i < 4; ++i) { sh[i] = FSQRT(hi[i]); sl[i] = FSQRT(lo[i]); }
#pragma unroll
    for (int k = 0; k < 16; ++k)
        amp[k] = sh[k >> 2] * sl[k & 3];
}

// amp for sample 0: little-endian bits, raw products, no sqrt
__device__ __forceinline__ void amp_prob2amp(f32x4 xv, float amp[16]) {
    float lo[4] = { (1.0f - xv.x) * (1.0f - xv.y), xv.x * (1.0f - xv.y),
                    (1.0f - xv.x) * xv.y,          xv.x * xv.y };
    float hi[4] = { (1.0f - xv.z) * (1.0f - xv.w), xv.z * (1.0f - xv.w),
                    (1.0f - xv.z) * xv.w,          xv.z * xv.w };
#pragma unroll
    for (int k = 0; k < 16; ++k)
        amp[k] = lo[k & 3] * hi[k >> 2];
}

#define TILES 2   // 2 x 256 samples per block; 2M / 512 = 4096 blocks = 2 gens

__global__ __launch_bounds__(256, 8) void vqc_main(const f32x4* __restrict__ x,
                                                   const float* __restrict__ T,
                                                   float* __restrict__ out,
                                                   int nsamp) {
    // wave-private double-buffered staging: [wave][buf][640 floats]
    __shared__ float sBuf[4][2][640];   // 20 KB

    int tid = threadIdx.x;
    int wid = tid >> 6;
    int lane = tid & 63;

    long long base = (long long)blockIdx.x * (TILES * 256);

    // prefetch tile 0 (nontemporal: x is read exactly once)
    f32x4 xv;
    {
        long long b0 = base + tid;
        if (b0 < nsamp) xv = __builtin_nontemporal_load(&x[b0]);
    }

#pragma unroll
    for (int t = 0; t < TILES; ++t) {
        long long tileStart = base + (long long)t * 256;
        long long b = tileStart + tid;
        f32x4 cur = xv;

        // issue next tile's load before this tile's compute (latency overlap)
        if (t + 1 < TILES) {
            long long bn = b + 256;
            if (bn < nsamp) xv = __builtin_nontemporal_load(&x[bn]);
        }

        int p = t & 1;
        float* myBuf = sBuf[wid][p];

        if (b < nsamp) {
            float amp[16];
            if (b == 0) amp_prob2amp(cur, amp);
            else        amp_resolve(cur, amp);

            // 10x16 matvec; T[] indices wave-uniform -> scalar loads feed
            // v_fmac as the single SGPR operand. unroll 2: ~32 live T-SGPRs.
#pragma unroll 2
            for (int c = 0; c < 10; ++c) {
                float s = 0.0f;
#pragma unroll
                for (int jj = 0; jj < 16; ++jj)
                    s = fmaf(T[c * 16 + jj], amp[jj], s);
                myBuf[lane * 10 + c] = s * s;   // 4-way bank alias: ~free
            }
        }

        // drain OWN ds ops - intra-wave only, no barrier (wave-private slice)
        asm volatile("s_waitcnt lgkmcnt(0)" ::: "memory");

        long long waveBase = tileStart + (long long)(wid << 6);
        long long wrem = (long long)nsamp - waveBase;
        if (wrem >= 64) {
            // wave's 64 samples = 2560B contiguous in out, line-aligned
            f32x4* ov = (f32x4*)(out + waveBase * 10);
            const f32x4* sv = (const f32x4*)myBuf;
#pragma unroll
            for (int i = lane; i < 160; i += 64)
                __builtin_nontemporal_store(sv[i], &ov[i]);
        } else if (wrem > 0) {
            int n = (int)wrem * 10;
            for (int i = lane; i < n; i += 64)
                out[waveBase * 10 + i] = myBuf[i];
        }
        // WAR on buffer p (reused at t+2): protected by the lgkmcnt(0) at
        // t+1, which drains this tile's flush ds_reads before t+2's writes.
    }
}

extern "C" void kernel_launch(void* const* d_in, const int* in_sizes, int n_in,
                              void* d_out, int out_size, void* d_ws, size_t ws_size,
                              hipStream_t stream) {
    const float* x = (const float*)d_in[0];      // [B,4] f32
    const float* theta = (const float*)d_in[1];  // [8]   f32
    float* out = (float*)d_out;                  // [B,10] f32
    float* T = (float*)d_ws;                     // 160 floats scratch

    int nsamp = in_sizes[0] / 4;

    build_T<<<1, 192, 0, stream>>>(theta, T);

    int spb = TILES * 256;
    int blocks = (nsamp + spb - 1) / spb;
    vqc_main<<<blocks, 256, 0, stream>>>((const f32x4*)x, T, out, nsamp);
}

// Round 11
// 29.161 us; speedup vs baseline: 1.0959x; 1.0959x over previous
//
#include <hip/hip_runtime.h>
#include <hip/hip_bf16.h>

// ---------------------------------------------------------------------------
// VQC_Net: probs[b, c] = ( sum_j U[c][j] * amp[b][j] )^2,  c = 0..9
// Structure: T = U rows 0..9 precomputed to d_ws by build_T; main kernel
// reads T with wave-uniform indices (s_load, K$-hot), c-outer matvec,
// wave-private LDS staging (no barriers, R8), persistent 4 tiles + prefetch.
// R11 delta (single change vs R8): NONTEMPORAL STORES on the output flush.
// out is written once and never read -> no-allocate stores avoid L2/L3
// dirty-line churn so x keeps its L2/L3 residency. Loads stay REGULAR:
// R10 lesson — NT loads kill x's inter-replay L3 residency (FETCH 16->32MB).
// Lessons kept: LDS transpose essential (R7: direct stride-40B stores = 10x
// line-request amplification -> 2.2 TB/s); no vmcnt-draining barriers (R6);
// LDS-read matvec = DS-pipe bound (R4); s_load matvec (R1); TILES=4 (R10).
// amp build:
//   amp[0][k]  = prod_j ( (k>>j)&1 ? x0j : 1-x0j )                 (no sqrt)
//   amp[b][k]  = sqrt(hi)*sqrt(lo) factored, big-endian bits       (b >= 1)
// ---------------------------------------------------------------------------

typedef float f32x4 __attribute__((ext_vector_type(4)));

#if defined(__has_builtin)
#if __has_builtin(__builtin_amdgcn_sqrtf)
#define FSQRT(x) __builtin_amdgcn_sqrtf(x)
#endif
#endif
#ifndef FSQRT
#define FSQRT(x) sqrtf(x)
#endif

__device__ __forceinline__ float ry_el(float c, float s, int i, int j) {
    return (i == j) ? c : (i ? s : -s);  // ry = [[c,-s],[s,c]]
}

__global__ void build_T(const float* __restrict__ theta, float* __restrict__ T) {
    int t = threadIdx.x;
    if (t >= 160) return;
    int c = t >> 4;   // row of U (class)
    int j = t & 15;   // col of U (amp index)

    float co1[4], si1[4], co2[4], si2[4];
#pragma unroll
    for (int q = 0; q < 4; ++q) {
        float h1 = 0.5f * theta[q];
        float h2 = 0.5f * theta[4 + q];
        co1[q] = cosf(h1); si1[q] = sinf(h1);
        co2[q] = cosf(h2); si2[q] = sinf(h2);
    }
    float acc = 0.0f;
#pragma unroll
    for (int k = 0; k < 16; ++k) {
        int k0 = k & 1, k1 = (k >> 1) & 1, k2 = (k >> 2) & 1, k3 = (k >> 3) & 1;
        float r2 = ry_el(co2[0], si2[0], c & 1, k0)
                 * ry_el(co2[1], si2[1], (c >> 1) & 1, k1)
                 * ry_el(co2[2], si2[2], (c >> 2) & 1, k2)
                 * ry_el(co2[3], si2[3], (c >> 3) & 1, k3);
        float r1 = ry_el(co1[0], si1[0], k0, j & 1)
                 * ry_el(co1[1], si1[1], k1, (j >> 1) & 1)
                 * ry_el(co1[2], si1[2], k2, (j >> 2) & 1)
                 * ry_el(co1[3], si1[3], k3, (j >> 3) & 1);
        int sgn = (k0 & k1) ^ (k1 & k2) ^ (k2 & k3) ^ (k0 & k3);
        acc = fmaf(sgn ? -r2 : r2, r1, acc);
    }
    T[c * 16 + j] = acc;   // row-major, matches matvec read order
}

// amp for the generic (b>=1) path: big-endian bits, squared probs, sqrt
__device__ __forceinline__ void amp_resolve(f32x4 xv, float amp[16]) {
    float p0 = xv.x * xv.x, p1 = xv.y * xv.y;
    float p2 = xv.z * xv.z, p3 = xv.w * xv.w;
    float hi[4] = { (1.0f - p0) * (1.0f - p1), (1.0f - p0) * p1,
                    p0 * (1.0f - p1),          p0 * p1 };
    float lo[4] = { (1.0f - p2) * (1.0f - p3), (1.0f - p2) * p3,
                    p2 * (1.0f - p3),          p2 * p3 };
    float sh[4], sl[4];
#pragma unroll
    for (int i = 0; i < 4; ++i) { sh[i] = FSQRT(hi[i]); sl[i] = FSQRT(lo[i]); }
#pragma unroll
    for (int k = 0; k < 16; ++k)
        amp[k] = sh[k >> 2] * sl[k & 3];
}

// amp for sample 0: little-endian bits, raw products, no sqrt
__device__ __forceinline__ void amp_prob2amp(f32x4 xv, float amp[16]) {
    float lo[4] = { (1.0f - xv.x) * (1.0f - xv.y), xv.x * (1.0f - xv.y),
                    (1.0f - xv.x) * xv.y,          xv.x * xv.y };
    float hi[4] = { (1.0f - xv.z) * (1.0f - xv.w), xv.z * (1.0f - xv.w),
                    (1.0f - xv.z) * xv.w,          xv.z * xv.w };
#pragma unroll
    for (int k = 0; k < 16; ++k)
        amp[k] = lo[k & 3] * hi[k >> 2];
}

#define TILES 4   // 4 x 256 samples per block; 2M / 1024 = 2048 blocks exact

__global__ __launch_bounds__(256, 8) void vqc_main(const f32x4* __restrict__ x,
                                                   const float* __restrict__ T,
                                                   float* __restrict__ out,
                                                   int nsamp) {
    // wave-private double-buffered staging: [wave][buf][640 floats]
    __shared__ float sBuf[4][2][640];   // 20 KB

    int tid = threadIdx.x;
    int wid = tid >> 6;
    int lane = tid & 63;

    long long base = (long long)blockIdx.x * (TILES * 256);

    // prefetch tile 0 (REGULAR load: x is L3-resident across replays)
    f32x4 xv;
    {
        long long b0 = base + tid;
        if (b0 < nsamp) xv = x[b0];
    }

#pragma unroll
    for (int t = 0; t < TILES; ++t) {
        long long tileStart = base + (long long)t * 256;
        long long b = tileStart + tid;
        f32x4 cur = xv;

        // issue next tile's load before this tile's compute (latency overlap)
        if (t + 1 < TILES) {
            long long bn = b + 256;
            if (bn < nsamp) xv = x[bn];
        }

        int p = t & 1;
        float* myBuf = sBuf[wid][p];

        if (b < nsamp) {
            float amp[16];
            if (b == 0) amp_prob2amp(cur, amp);
            else        amp_resolve(cur, amp);

            // 10x16 matvec; T[] indices wave-uniform -> scalar loads feed
            // v_fmac as the single SGPR operand. unroll 2: ~32 live T-SGPRs.
#pragma unroll 2
            for (int c = 0; c < 10; ++c) {
                float s = 0.0f;
#pragma unroll
                for (int jj = 0; jj < 16; ++jj)
                    s = fmaf(T[c * 16 + jj], amp[jj], s);
                myBuf[lane * 10 + c] = s * s;   // 4-way bank alias: ~free
            }
        }

        // drain OWN ds ops - intra-wave only, no barrier (wave-private slice)
        asm volatile("s_waitcnt lgkmcnt(0)" ::: "memory");

        long long waveBase = tileStart + (long long)(wid << 6);
        long long wrem = (long long)nsamp - waveBase;
        if (wrem >= 64) {
            // wave's 64 samples = 2560B contiguous in out, line-aligned.
            // NONTEMPORAL: out is write-once -> no-allocate, no L2/L3 churn.
            f32x4* ov = (f32x4*)(out + waveBase * 10);
            const f32x4* sv = (const f32x4*)myBuf;
#pragma unroll
            for (int i = lane; i < 160; i += 64)
                __builtin_nontemporal_store(sv[i], &ov[i]);
        } else if (wrem > 0) {
            int n = (int)wrem * 10;
            for (int i = lane; i < n; i += 64)
                out[waveBase * 10 + i] = myBuf[i];
        }
        // WAR on buffer p (reused at t+2): protected by the lgkmcnt(0) at
        // t+1, which drains this tile's flush ds_reads before t+2's writes.
    }
}

extern "C" void kernel_launch(void* const* d_in, const int* in_sizes, int n_in,
                              void* d_out, int out_size, void* d_ws, size_t ws_size,
                              hipStream_t stream) {
    const float* x = (const float*)d_in[0];      // [B,4] f32
    const float* theta = (const float*)d_in[1];  // [8]   f32
    float* out = (float*)d_out;                  // [B,10] f32
    float* T = (float*)d_ws;                     // 160 floats scratch

    int nsamp = in_sizes[0] / 4;

    build_T<<<1, 192, 0, stream>>>(theta, T);

    int spb = TILES * 256;
    int blocks = (nsamp + spb - 1) / spb;
    vqc_main<<<blocks, 256, 0, stream>>>((const f32x4*)x, T, out, nsamp);
}

// Round 12
// 27.676 us; speedup vs baseline: 1.1546x; 1.0536x over previous
//
#include <hip/hip_runtime.h>
#include <hip/hip_bf16.h>

// ---------------------------------------------------------------------------
// VQC_Net: probs[b, c] = ( sum_j U[c][j] * amp[b][j] )^2,  c = 0..9
// Structure: T = U rows 0..9 precomputed to d_ws by build_T; main kernel
// reads T with wave-uniform indices (s_load, K$-hot), c-outer matvec,
// wave-private LDS staging (no barriers, R8), NT stores (R11).
// R12 delta (single change vs R11): FRONT-LOAD all 4 tiles' x into registers
// at kernel entry (4 outstanding float4 loads, +12 VGPR). Steady state is a
// PURE store stream (fills hit 6.9 TB/s on pure stores); no mid-kernel read/
// write interleave, no mid-kernel load-latency exposure. vmem retires
// in-order: loads precede all stores, so xv waits never force store drains.
// Lessons kept: LDS transpose essential (R7: stride-40B stores = 10x line-
// request amplification -> 2.2 TB/s); no vmcnt-draining barriers (R6); NT
// loads kill inter-replay L3 residency of x (R10); LDS-read matvec = DS-pipe
// bound (R4); s_load matvec c-outer unroll-2 (R1); TILES=4, 2048 blocks.
// amp build:
//   amp[0][k]  = prod_j ( (k>>j)&1 ? x0j : 1-x0j )                 (no sqrt)
//   amp[b][k]  = sqrt(hi)*sqrt(lo) factored, big-endian bits       (b >= 1)
// ---------------------------------------------------------------------------

typedef float f32x4 __attribute__((ext_vector_type(4)));

#if defined(__has_builtin)
#if __has_builtin(__builtin_amdgcn_sqrtf)
#define FSQRT(x) __builtin_amdgcn_sqrtf(x)
#endif
#endif
#ifndef FSQRT
#define FSQRT(x) sqrtf(x)
#endif

__device__ __forceinline__ float ry_el(float c, float s, int i, int j) {
    return (i == j) ? c : (i ? s : -s);  // ry = [[c,-s],[s,c]]
}

__global__ void build_T(const float* __restrict__ theta, float* __restrict__ T) {
    int t = threadIdx.x;
    if (t >= 160) return;
    int c = t >> 4;   // row of U (class)
    int j = t & 15;   // col of U (amp index)

    float co1[4], si1[4], co2[4], si2[4];
#pragma unroll
    for (int q = 0; q < 4; ++q) {
        float h1 = 0.5f * theta[q];
        float h2 = 0.5f * theta[4 + q];
        co1[q] = cosf(h1); si1[q] = sinf(h1);
        co2[q] = cosf(h2); si2[q] = sinf(h2);
    }
    float acc = 0.0f;
#pragma unroll
    for (int k = 0; k < 16; ++k) {
        int k0 = k & 1, k1 = (k >> 1) & 1, k2 = (k >> 2) & 1, k3 = (k >> 3) & 1;
        float r2 = ry_el(co2[0], si2[0], c & 1, k0)
                 * ry_el(co2[1], si2[1], (c >> 1) & 1, k1)
                 * ry_el(co2[2], si2[2], (c >> 2) & 1, k2)
                 * ry_el(co2[3], si2[3], (c >> 3) & 1, k3);
        float r1 = ry_el(co1[0], si1[0], k0, j & 1)
                 * ry_el(co1[1], si1[1], k1, (j >> 1) & 1)
                 * ry_el(co1[2], si1[2], k2, (j >> 2) & 1)
                 * ry_el(co1[3], si1[3], k3, (j >> 3) & 1);
        int sgn = (k0 & k1) ^ (k1 & k2) ^ (k2 & k3) ^ (k0 & k3);
        acc = fmaf(sgn ? -r2 : r2, r1, acc);
    }
    T[c * 16 + j] = acc;   // row-major, matches matvec read order
}

// amp for the generic (b>=1) path: big-endian bits, squared probs, sqrt
__device__ __forceinline__ void amp_resolve(f32x4 xv, float amp[16]) {
    float p0 = xv.x * xv.x, p1 = xv.y * xv.y;
    float p2 = xv.z * xv.z, p3 = xv.w * xv.w;
    float hi[4] = { (1.0f - p0) * (1.0f - p1), (1.0f - p0) * p1,
                    p0 * (1.0f - p1),          p0 * p1 };
    float lo[4] = { (1.0f - p2) * (1.0f - p3), (1.0f - p2) * p3,
                    p2 * (1.0f - p3),          p2 * p3 };
    float sh[4], sl[4];
#pragma unroll
    for (int i = 0; i < 4; ++i) { sh[i] = FSQRT(hi[i]); sl[i] = FSQRT(lo[i]); }
#pragma unroll
    for (int k = 0; k < 16; ++k)
        amp[k] = sh[k >> 2] * sl[k & 3];
}

// amp for sample 0: little-endian bits, raw products, no sqrt
__device__ __forceinline__ void amp_prob2amp(f32x4 xv, float amp[16]) {
    float lo[4] = { (1.0f - xv.x) * (1.0f - xv.y), xv.x * (1.0f - xv.y),
                    (1.0f - xv.x) * xv.y,          xv.x * xv.y };
    float hi[4] = { (1.0f - xv.z) * (1.0f - xv.w), xv.z * (1.0f - xv.w),
                    (1.0f - xv.z) * xv.w,          xv.z * xv.w };
#pragma unroll
    for (int k = 0; k < 16; ++k)
        amp[k] = lo[k & 3] * hi[k >> 2];
}

#define TILES 4   // 4 x 256 samples per block; 2M / 1024 = 2048 blocks exact

__global__ __launch_bounds__(256, 8) void vqc_main(const f32x4* __restrict__ x,
                                                   const float* __restrict__ T,
                                                   float* __restrict__ out,
                                                   int nsamp) {
    // wave-private double-buffered staging: [wave][buf][640 floats]
    __shared__ float sBuf[4][2][640];   // 20 KB

    int tid = threadIdx.x;
    int wid = tid >> 6;
    int lane = tid & 63;

    long long base = (long long)blockIdx.x * (TILES * 256);

    // FRONT-LOAD all 4 tiles of x (issued back-to-back; 4 outstanding vmem).
    f32x4 xv[TILES];
#pragma unroll
    for (int t = 0; t < TILES; ++t) {
        long long bt = base + (long long)t * 256 + tid;
        if (bt < nsamp) xv[t] = x[bt];
    }

#pragma unroll
    for (int t = 0; t < TILES; ++t) {
        long long tileStart = base + (long long)t * 256;
        long long b = tileStart + tid;

        int p = t & 1;
        float* myBuf = sBuf[wid][p];

        if (b < nsamp) {
            float amp[16];
            if (b == 0) amp_prob2amp(xv[t], amp);
            else        amp_resolve(xv[t], amp);

            // 10x16 matvec; T[] indices wave-uniform -> scalar loads feed
            // v_fmac as the single SGPR operand. unroll 2: ~32 live T-SGPRs.
#pragma unroll 2
            for (int c = 0; c < 10; ++c) {
                float s = 0.0f;
#pragma unroll
                for (int jj = 0; jj < 16; ++jj)
                    s = fmaf(T[c * 16 + jj], amp[jj], s);
                myBuf[lane * 10 + c] = s * s;   // 4-way bank alias: ~free
            }
        }

        // drain OWN ds ops - intra-wave only, no barrier (wave-private slice)
        asm volatile("s_waitcnt lgkmcnt(0)" ::: "memory");

        long long waveBase = tileStart + (long long)(wid << 6);
        long long wrem = (long long)nsamp - waveBase;
        if (wrem >= 64) {
            // wave's 64 samples = 2560B contiguous in out, line-aligned.
            // NONTEMPORAL: out is write-once -> no-allocate, no L2/L3 churn.
            f32x4* ov = (f32x4*)(out + waveBase * 10);
            const f32x4* sv = (const f32x4*)myBuf;
#pragma unroll
            for (int i = lane; i < 160; i += 64)
                __builtin_nontemporal_store(sv[i], &ov[i]);
        } else if (wrem > 0) {
            int n = (int)wrem * 10;
            for (int i = lane; i < n; i += 64)
                out[waveBase * 10 + i] = myBuf[i];
        }
        // WAR on buffer p (reused at t+2): protected by the lgkmcnt(0) at
        // t+1, which drains this tile's flush ds_reads before t+2's writes.
    }
}

extern "C" void kernel_launch(void* const* d_in, const int* in_sizes, int n_in,
                              void* d_out, int out_size, void* d_ws, size_t ws_size,
                              hipStream_t stream) {
    const float* x = (const float*)d_in[0];      // [B,4] f32
    const float* theta = (const float*)d_in[1];  // [8]   f32
    float* out = (float*)d_out;                  // [B,10] f32
    float* T = (float*)d_ws;                     // 160 floats scratch

    int nsamp = in_sizes[0] / 4;

    build_T<<<1, 192, 0, stream>>>(theta, T);

    int spb = TILES * 256;
    int blocks = (nsamp + spb - 1) / spb;
    vqc_main<<<blocks, 256, 0, stream>>>((const f32x4*)x, T, out, nsamp);
}

// Round 13
// 23.899 us; speedup vs baseline: 1.3372x; 1.1581x over previous
//
#include <hip/hip_runtime.h>

// ---------------------------------------------------------------------------
// VQC_Net fully fused, SINGLE kernel: probs[b,c] = ((RY2 * D * RY1) amp)^2[c]
// R13: butterfly factorization (R2 math, correctness-proven) on the R12
// skeleton -> the build_T graph node disappears. The only uniform data is
// 16 cos/sin coefficients computed in-kernel via fast trig (v_cos/v_sin,
// ~48 inst one-time per thread, amortized over 4 tiles).
//   RY layer, qubit q, pair (i, i|1<<q): [c,-s; s,c]
//   D = diag sign: -1 exactly at k in {3, 6, 9, 12}
//   final stage computes only the 10 needed outputs.
// Skeleton lessons kept: wave-private LDS staging, zero barriers (R8);
// NT stores, regular loads (R10/R11); front-loaded x reads (R12);
// LDS transpose essential (R7: direct stride-40B stores = 10x line-request
// amplification); no vmcnt-draining waits (R6); TILES=4, 2048 blocks.
// amp build:
//   amp[0][k]  = prod_j ( (k>>j)&1 ? x0j : 1-x0j )                 (no sqrt)
//   amp[b][k]  = sqrt(hi)*sqrt(lo) factored, big-endian bits       (b >= 1)
// ---------------------------------------------------------------------------

typedef float f32x4 __attribute__((ext_vector_type(4)));

#if defined(__has_builtin)
#if __has_builtin(__builtin_amdgcn_sqrtf)
#define FSQRT(x) __builtin_amdgcn_sqrtf(x)
#endif
#endif
#ifndef FSQRT
#define FSQRT(x) sqrtf(x)
#endif

// amp for the generic (b>=1) path: big-endian bits, squared probs, sqrt
__device__ __forceinline__ void amp_resolve(f32x4 xv, float amp[16]) {
    float p0 = xv.x * xv.x, p1 = xv.y * xv.y;
    float p2 = xv.z * xv.z, p3 = xv.w * xv.w;
    float hi[4] = { (1.0f - p0) * (1.0f - p1), (1.0f - p0) * p1,
                    p0 * (1.0f - p1),          p0 * p1 };
    float lo[4] = { (1.0f - p2) * (1.0f - p3), (1.0f - p2) * p3,
                    p2 * (1.0f - p3),          p2 * p3 };
    float sh[4], sl[4];
#pragma unroll
    for (int i = 0; i < 4; ++i) { sh[i] = FSQRT(hi[i]); sl[i] = FSQRT(lo[i]); }
#pragma unroll
    for (int k = 0; k < 16; ++k)
        amp[k] = sh[k >> 2] * sl[k & 3];
}

// amp for sample 0: little-endian bits, raw products, no sqrt
__device__ __forceinline__ void amp_prob2amp(f32x4 xv, float amp[16]) {
    float lo[4] = { (1.0f - xv.x) * (1.0f - xv.y), xv.x * (1.0f - xv.y),
                    (1.0f - xv.x) * xv.y,          xv.x * xv.y };
    float hi[4] = { (1.0f - xv.z) * (1.0f - xv.w), xv.z * (1.0f - xv.w),
                    (1.0f - xv.z) * xv.w,          xv.z * xv.w };
#pragma unroll
    for (int k = 0; k < 16; ++k)
        amp[k] = lo[k & 3] * hi[k >> 2];
}

#define TILES 4   // 4 x 256 samples per block; 2M / 1024 = 2048 blocks exact

__global__ __launch_bounds__(256, 8) void vqc_main(const f32x4* __restrict__ x,
                                                   const float* __restrict__ theta,
                                                   float* __restrict__ out,
                                                   int nsamp) {
    // wave-private double-buffered staging: [wave][buf][640 floats]
    __shared__ float sBuf[4][2][640];   // 20 KB

    int tid = threadIdx.x;
    int wid = tid >> 6;
    int lane = tid & 63;

    long long base = (long long)blockIdx.x * (TILES * 256);

    // FRONT-LOAD all 4 tiles of x (issued back-to-back; 4 outstanding vmem).
    f32x4 xv[TILES];
#pragma unroll
    for (int t = 0; t < TILES; ++t) {
        long long bt = base + (long long)t * 256 + tid;
        if (bt < nsamp) xv[t] = x[bt];
    }

    // 16 uniform butterfly coefficients (theta uniform -> s_load; fast trig
    // hides under the outstanding x loads). One-time cost, amortized 4 tiles.
    float c1[4], s1[4], c2[4], s2[4];
#pragma unroll
    for (int q = 0; q < 4; ++q) {
        float h1 = 0.5f * theta[q];
        float h2 = 0.5f * theta[4 + q];
        c1[q] = __cosf(h1); s1[q] = __sinf(h1);
        c2[q] = __cosf(h2); s2[q] = __sinf(h2);
    }

#pragma unroll
    for (int t = 0; t < TILES; ++t) {
        long long tileStart = base + (long long)t * 256;
        long long b = tileStart + tid;

        int p = t & 1;
        float* myBuf = sBuf[wid][p];

        if (b < nsamp) {
            float amp[16];
            if (b == 0) amp_prob2amp(xv[t], amp);
            else        amp_resolve(xv[t], amp);

            // ---- U = RY2 * D * RY1 as butterflies (R2 math, proven) ----
#define BFLY(Q, CC, SS)                                                  \
            _Pragma("unroll")                                            \
            for (int i0 = 0; i0 < 16; ++i0)                              \
                if (!(i0 & (1 << (Q)))) {                                \
                    int i1 = i0 | (1 << (Q));                            \
                    float a0 = amp[i0], a1 = amp[i1];                    \
                    amp[i0] = fmaf((CC), a0, -(SS) * a1);                \
                    amp[i1] = fmaf((SS), a0,  (CC) * a1);                \
                }

            BFLY(0, c1[0], s1[0])
            BFLY(1, c1[1], s1[1])
            BFLY(2, c1[2], s1[2])
            BFLY(3, c1[3], s1[3])

            // D: sign flips at k = 3, 6, 9, 12
            amp[3]  = -amp[3];
            amp[6]  = -amp[6];
            amp[9]  = -amp[9];
            amp[12] = -amp[12];

            BFLY(0, c2[0], s2[0])
            BFLY(1, c2[1], s2[1])
            BFLY(2, c2[2], s2[2])
#undef BFLY

            // qubit-3 stage: only the 10 needed rows
            float r[10];
#pragma unroll
            for (int i = 0; i < 8; ++i)
                r[i] = fmaf(c2[3], amp[i], -s2[3] * amp[i + 8]);
            r[8] = fmaf(s2[3], amp[0], c2[3] * amp[8]);
            r[9] = fmaf(s2[3], amp[1], c2[3] * amp[9]);

#pragma unroll
            for (int c = 0; c < 10; ++c)
                myBuf[lane * 10 + c] = r[c] * r[c];   // 4-way bank alias: ~free
        }

        // drain OWN ds ops - intra-wave only, no barrier (wave-private slice)
        asm volatile("s_waitcnt lgkmcnt(0)" ::: "memory");

        long long waveBase = tileStart + (long long)(wid << 6);
        long long wrem = (long long)nsamp - waveBase;
        if (wrem >= 64) {
            // wave's 64 samples = 2560B contiguous in out, line-aligned.
            // NONTEMPORAL: out is write-once -> no-allocate, no L2/L3 churn.
            f32x4* ov = (f32x4*)(out + waveBase * 10);
            const f32x4* sv = (const f32x4*)myBuf;
#pragma unroll
            for (int i = lane; i < 160; i += 64)
                __builtin_nontemporal_store(sv[i], &ov[i]);
        } else if (wrem > 0) {
            int n = (int)wrem * 10;
            for (int i = lane; i < n; i += 64)
                out[waveBase * 10 + i] = myBuf[i];
        }
        // WAR on buffer p (reused at t+2): protected by the lgkmcnt(0) at
        // t+1, which drains this tile's flush ds_reads before t+2's writes.
    }
}

extern "C" void kernel_launch(void* const* d_in, const int* in_sizes, int n_in,
                              void* d_out, int out_size, void* d_ws, size_t ws_size,
                              hipStream_t stream) {
    const float* x = (const float*)d_in[0];      // [B,4] f32
    const float* theta = (const float*)d_in[1];  // [8]   f32
    float* out = (float*)d_out;                  // [B,10] f32

    int nsamp = in_sizes[0] / 4;
    int spb = TILES * 256;
    int blocks = (nsamp + spb - 1) / spb;
    vqc_main<<<blocks, 256, 0, stream>>>((const f32x4*)x, theta, out, nsamp);
}